// Round 6
// baseline (285.515 us; speedup 1.0000x reference)
//
#include <hip/hip_runtime.h>

// CausalSelfAttention: B=2,S=2048,H=2048,NH=16,NKV=4,HD=128, fp32 in/out,
// internal bf16 MFMA pipeline.
// Round 6: attn strip assignment balanced. Blocks all co-resident (2/CU, no
// dynamic rebalance); old mapping gave per-CU loads of 18..50 tile-units
// (avg 34.5) -> idle-tail makespan (observed 10.5% time-avg occupancy).
// New mapping pairs strip 63-k with strip k on the same CU => ~34.5 each.
// ws layout (bytes):
//   [0,16.8M)      xb (x cast bf16)          -> reused later: Qpk (16MB)
//   [16.8M,29.4M)  WqkvT bf16 [3072][2048]   -> reused later: Kpk(4MB)+Vpk(4MB)
//   [29.4M,37.7M)  WoT bf16 [2048][2048]
//   [37.7M,62.9M)  QKVb bf16 [4096][3072]    -> reused later: Y bf16 [4096][2048]

#define S_LEN 2048

typedef __bf16 bf16_t;
typedef bf16_t bf16x8 __attribute__((ext_vector_type(8)));
typedef float f32x4 __attribute__((ext_vector_type(4)));
typedef float f32x16 __attribute__((ext_vector_type(16)));
typedef unsigned int u32x4 __attribute__((ext_vector_type(4)));
typedef unsigned short u16x4 __attribute__((ext_vector_type(4)));

__device__ __forceinline__ unsigned short f2bf(float f) {
  unsigned int u = __builtin_bit_cast(unsigned int, f);
  u += 0x7fffu + ((u >> 16) & 1u);
  return (unsigned short)(u >> 16);
}
__device__ __forceinline__ float bf2f(unsigned short h) {
  return __builtin_bit_cast(float, (unsigned int)h << 16);
}
__device__ __forceinline__ unsigned pk2(float a, float b) {
  return (unsigned)f2bf(a) | ((unsigned)f2bf(b) << 16);
}

typedef const __attribute__((address_space(1))) unsigned int* gas1_t;
typedef __attribute__((address_space(3))) unsigned int* las3_t;
__device__ __forceinline__ void async16(const void* g, void* l) {
  __builtin_amdgcn_global_load_lds((gas1_t)g, (las3_t)l, 16, 0, 0);
}

__device__ __forceinline__ bf16x8 ldfrag(const void* p) {
  return __builtin_bit_cast(bf16x8, *(const u32x4*)p);
}
__device__ __forceinline__ f32x16 mfma32(bf16x8 a, bf16x8 b, f32x16 c) {
  return __builtin_amdgcn_mfma_f32_32x32x16_bf16(a, b, c, 0, 0, 0);
}
__device__ __forceinline__ f32x16 zero16() {
  f32x16 v;
#pragma unroll
  for (int i = 0; i < 16; i++) v[i] = 0.f;
  return v;
}

// ---------------- cast x fp32 -> bf16 ----------------
__global__ __launch_bounds__(256) void cast_x_kernel(
    const float* __restrict__ in, unsigned short* __restrict__ out, int n8) {
  int i = blockIdx.x * 256 + threadIdx.x;
  if (i >= n8) return;
  const f32x4* p = (const f32x4*)in + (size_t)i * 2;
  f32x4 a = p[0], b = p[1];
  u32x4 o;
  o.x = pk2(a.x, a.y);
  o.y = pk2(a.z, a.w);
  o.z = pk2(b.x, b.y);
  o.w = pk2(b.z, b.w);
  *(u32x4*)(out + (size_t)i * 8) = o;
}

// ---------------- transpose+cast: in fp32 [R][C] -> out bf16 [C][R] ----------------
__global__ __launch_bounds__(256) void transpose_cast_kernel(
    const float* __restrict__ in, unsigned short* __restrict__ out,
    int R, int C, int out_row_off, int out_ld) {
  __shared__ unsigned short L[64][68];
  int t = threadIdx.x;
  int r0 = blockIdx.y * 64, c0 = blockIdx.x * 64;
#pragma unroll
  for (int i = 0; i < 4; i++) {
    int r = i * 16 + (t >> 4);
    int c = (t & 15) * 4;
    f32x4 v = *(const f32x4*)&in[(size_t)(r0 + r) * C + c0 + c];
    u16x4 u;
    u.x = f2bf(v.x); u.y = f2bf(v.y); u.z = f2bf(v.z); u.w = f2bf(v.w);
    *(u16x4*)&L[r][c] = u;
  }
  __syncthreads();
#pragma unroll
  for (int i = 0; i < 4; i++) {
    int oc = i * 16 + (t >> 4);
    int orr = (t & 15) * 4;
    u16x4 u;
    u.x = L[orr + 0][oc]; u.y = L[orr + 1][oc];
    u.z = L[orr + 2][oc]; u.w = L[orr + 3][oc];
    *(u16x4*)&out[(size_t)(c0 + oc + out_row_off) * out_ld + r0 + orr] = u;
  }
}

// ---------------- bf16 GEMM: C[M][N] = A[M][K] * Bt[N][K]^T ----------------
__global__ __launch_bounds__(256) void gemm_bf16_kernel(
    const unsigned short* __restrict__ A, const unsigned short* __restrict__ Bt,
    void* __restrict__ Cout, int M, int N, int K, int out_bf16) {
  __shared__ unsigned short As[128 * 32];
  __shared__ unsigned short Bs[128 * 32];
  const int t = threadIdx.x, w = t >> 6, l = t & 63;
  const int wr = w >> 1, wc = w & 1;
  const int lrow = l & 15, lhi = l >> 4;
  const int row0 = blockIdx.y * 128, col0 = blockIdx.x * 128;
  const unsigned short* Ab = A + (size_t)row0 * K;
  const unsigned short* Bb = Bt + (size_t)col0 * K;
  const int srow = w * 32 + (l >> 2);
  const int scol = (l & 3) * 8;
  f32x4 z = {0.f, 0.f, 0.f, 0.f};
  f32x4 acc[4][4];
#pragma unroll
  for (int m = 0; m < 4; m++)
#pragma unroll
    for (int n = 0; n < 4; n++) acc[m][n] = z;

  for (int k0 = 0; k0 < K; k0 += 32) {
    async16(Ab + (size_t)srow * K + k0 + scol,        &As[(w * 32) * 32]);
    async16(Ab + (size_t)(srow + 16) * K + k0 + scol, &As[(w * 32 + 16) * 32]);
    async16(Bb + (size_t)srow * K + k0 + scol,        &Bs[(w * 32) * 32]);
    async16(Bb + (size_t)(srow + 16) * K + k0 + scol, &Bs[(w * 32 + 16) * 32]);
    __syncthreads();
    bf16x8 af[4], bfr[4];
#pragma unroll
    for (int m = 0; m < 4; m++)
      af[m] = ldfrag(&As[(wr * 64 + m * 16 + lrow) * 32 + lhi * 8]);
#pragma unroll
    for (int n = 0; n < 4; n++)
      bfr[n] = ldfrag(&Bs[(wc * 64 + n * 16 + lrow) * 32 + lhi * 8]);
#pragma unroll
    for (int m = 0; m < 4; m++)
#pragma unroll
      for (int n = 0; n < 4; n++)
        acc[m][n] = __builtin_amdgcn_mfma_f32_16x16x32_bf16(af[m], bfr[n], acc[m][n], 0, 0, 0);
    __syncthreads();
  }

  if (out_bf16) {
    unsigned short* C = (unsigned short*)Cout;
#pragma unroll
    for (int m = 0; m < 4; m++)
#pragma unroll
      for (int n = 0; n < 4; n++)
#pragma unroll
        for (int r = 0; r < 4; r++) {
          size_t grow = row0 + wr * 64 + m * 16 + lhi * 4 + r;
          size_t gcol = col0 + wc * 64 + n * 16 + lrow;
          C[grow * N + gcol] = f2bf(acc[m][n][r]);
        }
  } else {
    float* C = (float*)Cout;
#pragma unroll
    for (int m = 0; m < 4; m++)
#pragma unroll
      for (int n = 0; n < 4; n++)
#pragma unroll
        for (int r = 0; r < 4; r++) {
          size_t grow = row0 + wr * 64 + m * 16 + lhi * 4 + r;
          size_t gcol = col0 + wc * 64 + n * 16 + lrow;
          C[grow * N + gcol] = acc[m][n][r];
        }
  }
}

// ---------------- mid: RMSNorm + RoPE, write fragment-packed Q/K/V ----------------
// Packed layouts (all fragment loads in attn become base + lane*16B):
//  Qpk[bh][strip=s/32][mf 0..7][hi 0..1][q31=s%32][j 0..7]   (4096 elems/strip)
//  Kpk[b*4+kvh][blk=s/32][mf][hi][kv31=s%32][j]              (4096 elems/blk)
//  Vpk[b*4+kvh][kv0=s/64][n 0..3][ks 0..3][hi=(s%16)/8][d31=d%32][j=s%8]
//                                                            (8192 elems/tile)
// Q gets (1/sqrt(128))*log2(e) baked in (attention works in exp2 units).
__global__ __launch_bounds__(256) void mid_kernel(
    const unsigned short* __restrict__ QKV, const float* __restrict__ cosT,
    const float* __restrict__ sinT, const float* __restrict__ qw,
    const float* __restrict__ kw, unsigned short* __restrict__ Qpk,
    unsigned short* __restrict__ Kpk, unsigned short* __restrict__ Vpk) {
  int w = threadIdx.x >> 6, l = threadIdx.x & 63;
  int g = blockIdx.x * 4 + w;
  int bs = g / 24, idx = g - bs * 24;
  int b = bs >> 11, s = bs & 2047;
  int d0 = 2 * l;
  unsigned int uu = *(const unsigned int*)(QKV + (size_t)bs * 3072 + idx * 128 + d0);
  float x0 = bf2f((unsigned short)(uu & 0xffffu));
  float x1 = bf2f((unsigned short)(uu >> 16));
  if (idx < 20) {
    const float* nw = (idx < 16) ? qw : kw;
    float ss = x0 * x0 + x1 * x1;
#pragma unroll
    for (int mk = 1; mk < 64; mk <<= 1) ss += __shfl_xor(ss, mk);
    float inv = rsqrtf(ss * (1.0f / 128.0f) + 1e-6f);
    float n0 = x0 * inv * nw[d0], n1 = x1 * inv * nw[d0 + 1];
    float p0 = __shfl_xor(n0, 32), p1 = __shfl_xor(n1, 32);
    float sg = (l < 32) ? -1.0f : 1.0f;
    float c0 = cosT[s * 128 + d0], c1 = cosT[s * 128 + d0 + 1];
    float sn0 = sinT[s * 128 + d0], sn1 = sinT[s * 128 + d0 + 1];
    float o0 = n0 * c0 + sg * p0 * sn0;
    float o1 = n1 * c1 + sg * p1 * sn1;
    // fragment coords for elements d0, d0+1 (same frag: d0 even)
    int mf = d0 >> 4, hi = (d0 >> 3) & 1, j = d0 & 7;
    int blk = s >> 5, r31 = s & 31;
    int foff = (mf * 2 + hi) * 256 + r31 * 8 + j;
    unsigned short* dst;
    if (idx < 16) {
      const float qs = 0.08838834764831845f * 1.4426950408889634f;  // 1/sqrt(128)*log2e
      o0 *= qs; o1 *= qs;
      dst = Qpk + (((size_t)(b * 16 + idx)) * 64 + blk) * 4096 + foff;
    } else {
      dst = Kpk + (((size_t)(b * 4 + (idx - 16))) * 64 + blk) * 4096 + foff;
    }
    *(unsigned int*)dst = pk2(o0, o1);
  } else {
    int kvh = idx - 20;
    // V: kv index = s, d indices = d0, d0+1
    int kv0 = s >> 6, ks = (s >> 4) & 3, his = (s >> 3) & 1, j = s & 7;
    int n = d0 >> 5, d31 = d0 & 31;
    size_t base = (((size_t)(b * 4 + kvh)) * 32 + kv0) * 8192 +
                  (((n * 4 + ks) * 2 + his) * 256 + d31 * 8 + j);
    Vpk[base] = f2bf(x0);
    Vpk[base + 8] = f2bf(x1);   // d0+1 -> d31+1
  }
}

// ---------------- flash attention: async-LDS double-buffered pipeline ----------------
// 512 blocks x 4 waves. Block = (b,kvh,strip); wave w = head kvh*4+w.
// bid&7 -> (b,kvh) (XCD-pinned K/V). Strip mapping pairs heavy+light on the
// same CU: j=bid>>3; j<32 -> strip 63-j (heavy, launched first), j>=32 ->
// strip j-32 (light). With XCD round-robin dispatch, CU k in an XCD gets
// j=k and j=k+32 => nt(63-k)+nt(k) ~= 34.5 tile-units for every k.
// Per KV tile (64 rows): stage K(16KB)+V(16KB) into LDS via 8 global_load_lds
// per wave (packed layout == linear), double-buffered; counted vmcnt(8) keeps
// the next tile's stage in flight across the raw s_barrier.
__global__ __launch_bounds__(256) void attn_kernel(
    const unsigned short* __restrict__ Qpk, const unsigned short* __restrict__ Kpk,
    const unsigned short* __restrict__ Vpk, unsigned short* __restrict__ Y) {
  __shared__ unsigned short Ks[2][8192];
  __shared__ unsigned short Vs[2][8192];
  const int w = threadIdx.x >> 6, l = threadIdx.x & 63;
  const int q31 = l & 31, hi = l >> 5;
  const int bid = blockIdx.x;
  const int xcd = bid & 7;
  const int b = xcd >> 2, kvh = xcd & 3;
  const int h = kvh * 4 + w;
  const int bh = b * 16 + h;
  const int j = bid >> 3;
  const int strip = (j < 32) ? (63 - j) : (j - 32);   // balanced pairing
  const int q0w = strip * 32;
  const int qg = q0w + q31;
  const unsigned short* Qs = Qpk + (((size_t)bh * 64 + strip) * 4096) + (size_t)l * 8;
  const unsigned short* Kg = Kpk + (size_t)(b * 4 + kvh) * 262144;
  const unsigned short* Vg = Vpk + (size_t)(b * 4 + kvh) * 262144;

#define STAGE_TILE(ti, buf)                                                    \
  {                                                                            \
    const unsigned short* kg_ = Kg + (size_t)(ti) * 8192;                      \
    const unsigned short* vg_ = Vg + (size_t)(ti) * 8192;                      \
    _Pragma("unroll")                                                          \
    for (int i_ = 0; i_ < 4; i_++) {                                           \
      int seg_ = i_ * 4 + w;                                                   \
      async16(kg_ + (size_t)(seg_ * 64 + l) * 8, &Ks[buf][seg_ * 512]);        \
      async16(vg_ + (size_t)(seg_ * 64 + l) * 8, &Vs[buf][seg_ * 512]);        \
    }                                                                          \
  }

  bf16x8 qf[8];
#pragma unroll
  for (int mf = 0; mf < 8; mf++)
    qf[mf] = ldfrag(Qs + mf * 512);
  asm volatile("s_waitcnt vmcnt(0)" ::: "memory");  // Q resolved before staging

  STAGE_TILE(0, 0);

  f32x16 o[4];
#pragma unroll
  for (int n = 0; n < 4; n++) o[n] = zero16();
  float m = -3.0e38f, lsum = 0.f;

  const int nt = (q0w + 95) >> 6;
  for (int ti = 0; ti < nt; ti++) {
    const int cur = ti & 1;
    const int kv0 = ti << 6;
    if (ti + 1 < nt) {
      STAGE_TILE(ti + 1, cur ^ 1);
      asm volatile("s_waitcnt vmcnt(8)" ::: "memory");  // current tile landed; next in flight
    } else {
      asm volatile("s_waitcnt vmcnt(0)" ::: "memory");
    }
    __builtin_amdgcn_s_barrier();
    __builtin_amdgcn_sched_barrier(0);

    // ---- QK^T (swapped): A=K fragments, B=Q fragments, from LDS ----
    f32x16 s0 = zero16(), s1 = zero16();
    const unsigned short* kt = &Ks[cur][0];
    __builtin_amdgcn_s_setprio(1);
#pragma unroll
    for (int mf = 0; mf < 8; mf++) {
      s0 = mfma32(ldfrag(kt + mf * 512 + l * 8), qf[mf], s0);
      s1 = mfma32(ldfrag(kt + 4096 + mf * 512 + l * 8), qf[mf], s1);
    }
    __builtin_amdgcn_s_setprio(0);
    // ---- causal mask (last tile only) ----
    if (ti == nt - 1) {
      const int kvb = kv0 + 4 * hi;
#pragma unroll
      for (int r = 0; r < 16; r++) {
        int kv = kvb + (r & 3) + 8 * (r >> 2);
        if (kv > qg) s0[r] = -3.0e38f;
        if (kv + 32 > qg) s1[r] = -3.0e38f;
      }
    }
    // ---- online softmax, lane-local row (exp2 units) ----
    float pm = s0[0];
#pragma unroll
    for (int r = 1; r < 16; r++) pm = fmaxf(pm, s0[r]);
#pragma unroll
    for (int r = 0; r < 16; r++) pm = fmaxf(pm, s1[r]);
    pm = fmaxf(pm, __shfl_xor(pm, 32));
    if (__any(pm > m + 8.0f)) {          // defer-max: skip rescale when bounded
      float mn = fmaxf(m, pm);
      float scl = exp2f(m - mn);
      m = mn;
      lsum *= scl;
#pragma unroll
      for (int r = 0; r < 16; r++) {
        float sr = __shfl(scl, (r & 3) + 8 * (r >> 2) + 4 * hi);
        o[0][r] *= sr; o[1][r] *= sr; o[2][r] *= sr; o[3][r] *= sr;
      }
    }
#pragma unroll
    for (int r = 0; r < 16; r++) {
      s0[r] = exp2f(s0[r] - m);
      s1[r] = exp2f(s1[r] - m);
    }
    float ts = 0.f;
#pragma unroll
    for (int r = 0; r < 16; r++) ts += s0[r] + s1[r];
    ts += __shfl_xor(ts, 32);
    lsum += ts;
    // ---- pack P -> A-operand fragments (pure register exchange) ----
    bf16x8 paf[4];
#pragma unroll
    for (int blk = 0; blk < 2; blk++) {
      f32x16& sx = blk ? s1 : s0;
#pragma unroll
      for (int blk2 = 0; blk2 < 2; blk2++) {
        const int base = 8 * blk2;
        unsigned g00 = pk2(sx[base + 0], sx[base + 1]);
        unsigned g01 = pk2(sx[base + 2], sx[base + 3]);
        unsigned g10 = pk2(sx[base + 4], sx[base + 5]);
        unsigned g11 = pk2(sx[base + 6], sx[base + 7]);
        unsigned snd0 = hi ? g00 : g10;   // partner needs regs indexed by ITS hi
        unsigned snd1 = hi ? g01 : g11;
        unsigned r0 = (unsigned)__shfl_xor((int)snd0, 32);
        unsigned r1 = (unsigned)__shfl_xor((int)snd1, 32);
        unsigned own0 = hi ? g10 : g00;
        unsigned own1 = hi ? g11 : g01;
        u32x4 wv;
        wv.x = hi ? r0 : own0;
        wv.y = hi ? r1 : own1;
        wv.z = hi ? own0 : r0;
        wv.w = hi ? own1 : r1;
        paf[blk * 2 + blk2] = __builtin_bit_cast(bf16x8, wv);
      }
    }
    // ---- PV: O[q][d] += P * V, V fragments from LDS ----
    const unsigned short* vt = &Vs[cur][0];
    __builtin_amdgcn_s_setprio(1);
#pragma unroll
    for (int n = 0; n < 4; n++) {
#pragma unroll
      for (int ks = 0; ks < 4; ks++)
        o[n] = mfma32(paf[ks], ldfrag(vt + (n * 4 + ks) * 512 + l * 8), o[n]);
    }
    __builtin_amdgcn_s_setprio(0);

    __builtin_amdgcn_sched_barrier(0);
    __builtin_amdgcn_s_barrier();   // all waves done reading buf[cur] before restage
  }
#undef STAGE_TILE
  // ---- epilogue: normalize rows, store ----
  float linv = 1.0f / lsum;
#pragma unroll
  for (int r = 0; r < 16; r++) {
    int cr = (r & 3) + 8 * (r >> 2) + 4 * hi;
    float lr = __shfl(linv, cr);
    int qrow = q0w + cr;
    size_t rowoff = ((size_t)(b * S_LEN + qrow)) * 2048 + h * 128 + q31;
    Y[rowoff]      = f2bf(o[0][r] * lr);
    Y[rowoff + 32] = f2bf(o[1][r] * lr);
    Y[rowoff + 64] = f2bf(o[2][r] * lr);
    Y[rowoff + 96] = f2bf(o[3][r] * lr);
  }
}

// ---------------- launch ----------------
extern "C" void kernel_launch(void* const* d_in, const int* in_sizes, int n_in,
                              void* d_out, int out_size, void* d_ws, size_t ws_size,
                              hipStream_t stream) {
  const float* x  = (const float*)d_in[0];
  const float* rc = (const float*)d_in[1];
  const float* rs = (const float*)d_in[2];
  const float* Wq = (const float*)d_in[3];
  const float* Wk = (const float*)d_in[4];
  const float* Wv = (const float*)d_in[5];
  const float* Wo = (const float*)d_in[6];
  const float* qw = (const float*)d_in[7];
  const float* kw = (const float*)d_in[8];
  float* out = (float*)d_out;
  char* ws = (char*)d_ws;

  unsigned short* xb   = (unsigned short*)(ws + 0);
  unsigned short* WT   = (unsigned short*)(ws + 16777216);
  unsigned short* WoT  = (unsigned short*)(ws + 29360128);
  unsigned short* QKVb = (unsigned short*)(ws + 37748736);
  unsigned short* Qpk  = (unsigned short*)(ws + 0);          // over xb (dead)
  unsigned short* Kpk  = (unsigned short*)(ws + 16777216);   // over WT (dead)
  unsigned short* Vpk  = (unsigned short*)(ws + 20971520);   // over WT (dead)
  unsigned short* Yb   = (unsigned short*)(ws + 37748736);   // over QKVb (dead)

  cast_x_kernel<<<4096, 256, 0, stream>>>(x, xb, 1048576);
  transpose_cast_kernel<<<dim3(32, 32), 256, 0, stream>>>(Wq, WT, 2048, 2048, 0, 2048);
  transpose_cast_kernel<<<dim3(8, 32), 256, 0, stream>>>(Wk, WT, 2048, 512, 2048, 2048);
  transpose_cast_kernel<<<dim3(8, 32), 256, 0, stream>>>(Wv, WT, 2048, 512, 2560, 2048);
  transpose_cast_kernel<<<dim3(32, 32), 256, 0, stream>>>(Wo, WoT, 2048, 2048, 0, 2048);
  gemm_bf16_kernel<<<dim3(24, 32), 256, 0, stream>>>(xb, WT, QKVb, 4096, 3072, 2048, 1);
  mid_kernel<<<24576, 256, 0, stream>>>(QKVb, rc, rs, qw, kw, Qpk, Kpk, Vpk);
  attn_kernel<<<512, 256, 0, stream>>>(Qpk, Kpk, Vpk, Yb);
  gemm_bf16_kernel<<<dim3(16, 32), 256, 0, stream>>>(Yb, WoT, out, 4096, 2048, 2048, 0);
}

// Round 7
// 264.131 us; speedup vs baseline: 1.0810x; 1.0810x over previous
//
#include <hip/hip_runtime.h>

// CausalSelfAttention: B=2,S=2048,H=2048,NH=16,NKV=4,HD=128, fp32 in/out,
// internal bf16 MFMA pipeline.
// Round 7: (a) equal-work attn blocks -- 256 blocks, block (b,kvh,pj) runs
// strips 63-pj then pj sequentially: nt sum == 33 for every block, so the
// makespan no longer depends on block->CU dispatch (r6 lesson: it isn't
// what we assumed). (b) v_cvt_pk_bf16_f32 for the P->bf16 pack (was ~160
// VALU slots/tile of hand-rolled f2bf; busy-phase VALU measured ~70%).
// ws layout (bytes):
//   [0,16.8M)      xb (x cast bf16)          -> reused later: Qpk (16MB)
//   [16.8M,29.4M)  WqkvT bf16 [3072][2048]   -> reused later: Kpk(4MB)+Vpk(4MB)
//   [29.4M,37.7M)  WoT bf16 [2048][2048]
//   [37.7M,62.9M)  QKVb bf16 [4096][3072]    -> reused later: Y bf16 [4096][2048]

#define S_LEN 2048

typedef __bf16 bf16_t;
typedef bf16_t bf16x8 __attribute__((ext_vector_type(8)));
typedef float f32x4 __attribute__((ext_vector_type(4)));
typedef float f32x16 __attribute__((ext_vector_type(16)));
typedef unsigned int u32x4 __attribute__((ext_vector_type(4)));
typedef unsigned short u16x4 __attribute__((ext_vector_type(4)));

__device__ __forceinline__ unsigned short f2bf(float f) {
  unsigned int u = __builtin_bit_cast(unsigned int, f);
  u += 0x7fffu + ((u >> 16) & 1u);
  return (unsigned short)(u >> 16);
}
__device__ __forceinline__ float bf2f(unsigned short h) {
  return __builtin_bit_cast(float, (unsigned int)h << 16);
}
__device__ __forceinline__ unsigned pk2(float a, float b) {
  return (unsigned)f2bf(a) | ((unsigned)f2bf(b) << 16);
}
// HW packed convert: lo = bf16(a), hi = bf16(b). Single VALU instruction.
__device__ __forceinline__ unsigned cvtpk(float a, float b) {
  unsigned r;
  asm("v_cvt_pk_bf16_f32 %0, %1, %2" : "=v"(r) : "v"(a), "v"(b));
  return r;
}

typedef const __attribute__((address_space(1))) unsigned int* gas1_t;
typedef __attribute__((address_space(3))) unsigned int* las3_t;
__device__ __forceinline__ void async16(const void* g, void* l) {
  __builtin_amdgcn_global_load_lds((gas1_t)g, (las3_t)l, 16, 0, 0);
}

__device__ __forceinline__ bf16x8 ldfrag(const void* p) {
  return __builtin_bit_cast(bf16x8, *(const u32x4*)p);
}
__device__ __forceinline__ f32x16 mfma32(bf16x8 a, bf16x8 b, f32x16 c) {
  return __builtin_amdgcn_mfma_f32_32x32x16_bf16(a, b, c, 0, 0, 0);
}
__device__ __forceinline__ f32x16 zero16() {
  f32x16 v;
#pragma unroll
  for (int i = 0; i < 16; i++) v[i] = 0.f;
  return v;
}

// ---------------- cast x fp32 -> bf16 ----------------
__global__ __launch_bounds__(256) void cast_x_kernel(
    const float* __restrict__ in, unsigned short* __restrict__ out, int n8) {
  int i = blockIdx.x * 256 + threadIdx.x;
  if (i >= n8) return;
  const f32x4* p = (const f32x4*)in + (size_t)i * 2;
  f32x4 a = p[0], b = p[1];
  u32x4 o;
  o.x = pk2(a.x, a.y);
  o.y = pk2(a.z, a.w);
  o.z = pk2(b.x, b.y);
  o.w = pk2(b.z, b.w);
  *(u32x4*)(out + (size_t)i * 8) = o;
}

// ---------------- transpose+cast: in fp32 [R][C] -> out bf16 [C][R] ----------------
__global__ __launch_bounds__(256) void transpose_cast_kernel(
    const float* __restrict__ in, unsigned short* __restrict__ out,
    int R, int C, int out_row_off, int out_ld) {
  __shared__ unsigned short L[64][68];
  int t = threadIdx.x;
  int r0 = blockIdx.y * 64, c0 = blockIdx.x * 64;
#pragma unroll
  for (int i = 0; i < 4; i++) {
    int r = i * 16 + (t >> 4);
    int c = (t & 15) * 4;
    f32x4 v = *(const f32x4*)&in[(size_t)(r0 + r) * C + c0 + c];
    u16x4 u;
    u.x = f2bf(v.x); u.y = f2bf(v.y); u.z = f2bf(v.z); u.w = f2bf(v.w);
    *(u16x4*)&L[r][c] = u;
  }
  __syncthreads();
#pragma unroll
  for (int i = 0; i < 4; i++) {
    int oc = i * 16 + (t >> 4);
    int orr = (t & 15) * 4;
    u16x4 u;
    u.x = L[orr + 0][oc]; u.y = L[orr + 1][oc];
    u.z = L[orr + 2][oc]; u.w = L[orr + 3][oc];
    *(u16x4*)&out[(size_t)(c0 + oc + out_row_off) * out_ld + r0 + orr] = u;
  }
}

// ---------------- bf16 GEMM: C[M][N] = A[M][K] * Bt[N][K]^T ----------------
__global__ __launch_bounds__(256) void gemm_bf16_kernel(
    const unsigned short* __restrict__ A, const unsigned short* __restrict__ Bt,
    void* __restrict__ Cout, int M, int N, int K, int out_bf16) {
  __shared__ unsigned short As[128 * 32];
  __shared__ unsigned short Bs[128 * 32];
  const int t = threadIdx.x, w = t >> 6, l = t & 63;
  const int wr = w >> 1, wc = w & 1;
  const int lrow = l & 15, lhi = l >> 4;
  const int row0 = blockIdx.y * 128, col0 = blockIdx.x * 128;
  const unsigned short* Ab = A + (size_t)row0 * K;
  const unsigned short* Bb = Bt + (size_t)col0 * K;
  const int srow = w * 32 + (l >> 2);
  const int scol = (l & 3) * 8;
  f32x4 z = {0.f, 0.f, 0.f, 0.f};
  f32x4 acc[4][4];
#pragma unroll
  for (int m = 0; m < 4; m++)
#pragma unroll
    for (int n = 0; n < 4; n++) acc[m][n] = z;

  for (int k0 = 0; k0 < K; k0 += 32) {
    async16(Ab + (size_t)srow * K + k0 + scol,        &As[(w * 32) * 32]);
    async16(Ab + (size_t)(srow + 16) * K + k0 + scol, &As[(w * 32 + 16) * 32]);
    async16(Bb + (size_t)srow * K + k0 + scol,        &Bs[(w * 32) * 32]);
    async16(Bb + (size_t)(srow + 16) * K + k0 + scol, &Bs[(w * 32 + 16) * 32]);
    __syncthreads();
    bf16x8 af[4], bfr[4];
#pragma unroll
    for (int m = 0; m < 4; m++)
      af[m] = ldfrag(&As[(wr * 64 + m * 16 + lrow) * 32 + lhi * 8]);
#pragma unroll
    for (int n = 0; n < 4; n++)
      bfr[n] = ldfrag(&Bs[(wc * 64 + n * 16 + lrow) * 32 + lhi * 8]);
#pragma unroll
    for (int m = 0; m < 4; m++)
#pragma unroll
      for (int n = 0; n < 4; n++)
        acc[m][n] = __builtin_amdgcn_mfma_f32_16x16x32_bf16(af[m], bfr[n], acc[m][n], 0, 0, 0);
    __syncthreads();
  }

  if (out_bf16) {
    unsigned short* C = (unsigned short*)Cout;
#pragma unroll
    for (int m = 0; m < 4; m++)
#pragma unroll
      for (int n = 0; n < 4; n++)
#pragma unroll
        for (int r = 0; r < 4; r++) {
          size_t grow = row0 + wr * 64 + m * 16 + lhi * 4 + r;
          size_t gcol = col0 + wc * 64 + n * 16 + lrow;
          C[grow * N + gcol] = f2bf(acc[m][n][r]);
        }
  } else {
    float* C = (float*)Cout;
#pragma unroll
    for (int m = 0; m < 4; m++)
#pragma unroll
      for (int n = 0; n < 4; n++)
#pragma unroll
        for (int r = 0; r < 4; r++) {
          size_t grow = row0 + wr * 64 + m * 16 + lhi * 4 + r;
          size_t gcol = col0 + wc * 64 + n * 16 + lrow;
          C[grow * N + gcol] = acc[m][n][r];
        }
  }
}

// ---------------- mid: RMSNorm + RoPE, write fragment-packed Q/K/V ----------------
// Packed layouts (all fragment loads in attn become base + lane*16B):
//  Qpk[bh][strip=s/32][mf 0..7][hi 0..1][q31=s%32][j 0..7]   (4096 elems/strip)
//  Kpk[b*4+kvh][blk=s/32][mf][hi][kv31=s%32][j]              (4096 elems/blk)
//  Vpk[b*4+kvh][kv0=s/64][n 0..3][ks 0..3][hi=(s%16)/8][d31=d%32][j=s%8]
//                                                            (8192 elems/tile)
// Q gets (1/sqrt(128))*log2(e) baked in (attention works in exp2 units).
__global__ __launch_bounds__(256) void mid_kernel(
    const unsigned short* __restrict__ QKV, const float* __restrict__ cosT,
    const float* __restrict__ sinT, const float* __restrict__ qw,
    const float* __restrict__ kw, unsigned short* __restrict__ Qpk,
    unsigned short* __restrict__ Kpk, unsigned short* __restrict__ Vpk) {
  int w = threadIdx.x >> 6, l = threadIdx.x & 63;
  int g = blockIdx.x * 4 + w;
  int bs = g / 24, idx = g - bs * 24;
  int b = bs >> 11, s = bs & 2047;
  int d0 = 2 * l;
  unsigned int uu = *(const unsigned int*)(QKV + (size_t)bs * 3072 + idx * 128 + d0);
  float x0 = bf2f((unsigned short)(uu & 0xffffu));
  float x1 = bf2f((unsigned short)(uu >> 16));
  if (idx < 20) {
    const float* nw = (idx < 16) ? qw : kw;
    float ss = x0 * x0 + x1 * x1;
#pragma unroll
    for (int mk = 1; mk < 64; mk <<= 1) ss += __shfl_xor(ss, mk);
    float inv = rsqrtf(ss * (1.0f / 128.0f) + 1e-6f);
    float n0 = x0 * inv * nw[d0], n1 = x1 * inv * nw[d0 + 1];
    float p0 = __shfl_xor(n0, 32), p1 = __shfl_xor(n1, 32);
    float sg = (l < 32) ? -1.0f : 1.0f;
    float c0 = cosT[s * 128 + d0], c1 = cosT[s * 128 + d0 + 1];
    float sn0 = sinT[s * 128 + d0], sn1 = sinT[s * 128 + d0 + 1];
    float o0 = n0 * c0 + sg * p0 * sn0;
    float o1 = n1 * c1 + sg * p1 * sn1;
    // fragment coords for elements d0, d0+1 (same frag: d0 even)
    int mf = d0 >> 4, hi = (d0 >> 3) & 1, j = d0 & 7;
    int blk = s >> 5, r31 = s & 31;
    int foff = (mf * 2 + hi) * 256 + r31 * 8 + j;
    unsigned short* dst;
    if (idx < 16) {
      const float qs = 0.08838834764831845f * 1.4426950408889634f;  // 1/sqrt(128)*log2e
      o0 *= qs; o1 *= qs;
      dst = Qpk + (((size_t)(b * 16 + idx)) * 64 + blk) * 4096 + foff;
    } else {
      dst = Kpk + (((size_t)(b * 4 + (idx - 16))) * 64 + blk) * 4096 + foff;
    }
    *(unsigned int*)dst = pk2(o0, o1);
  } else {
    int kvh = idx - 20;
    // V: kv index = s, d indices = d0, d0+1
    int kv0 = s >> 6, ks = (s >> 4) & 3, his = (s >> 3) & 1, j = s & 7;
    int n = d0 >> 5, d31 = d0 & 31;
    size_t base = (((size_t)(b * 4 + kvh)) * 32 + kv0) * 8192 +
                  (((n * 4 + ks) * 2 + his) * 256 + d31 * 8 + j);
    Vpk[base] = f2bf(x0);
    Vpk[base + 8] = f2bf(x1);   // d0+1 -> d31+1
  }
}

// ---------------- flash attention: async-LDS double-buffered pipeline ----------------
// 256 equal-work blocks x 4 waves. Block = (b,kvh,pj); wave w = head kvh*4+w.
// bid&7 -> (b,kvh) (XCD-pinned K/V). Block runs strip 63-pj then strip pj
// sequentially: nt(63-pj)+nt(pj) == 33 for every pj -> no dependence on
// block->CU dispatch (r6: dispatch-order assumptions fail).
// Per KV tile (64 rows): stage K(16KB)+V(16KB) into LDS via 8 global_load_lds
// per wave (packed layout == linear), double-buffered; counted vmcnt(8) keeps
// the next tile's stage in flight across the raw s_barrier.
__global__ __launch_bounds__(256) void attn_kernel(
    const unsigned short* __restrict__ Qpk, const unsigned short* __restrict__ Kpk,
    const unsigned short* __restrict__ Vpk, unsigned short* __restrict__ Y) {
  __shared__ unsigned short Ks[2][8192];
  __shared__ unsigned short Vs[2][8192];
  const int w = threadIdx.x >> 6, l = threadIdx.x & 63;
  const int q31 = l & 31, hi = l >> 5;
  const int bid = blockIdx.x;
  const int xcd = bid & 7;
  const int b = xcd >> 2, kvh = xcd & 3;
  const int h = kvh * 4 + w;
  const int bh = b * 16 + h;
  const int pj = bid >> 3;             // 0..31
  const unsigned short* Kg = Kpk + (size_t)(b * 4 + kvh) * 262144;
  const unsigned short* Vg = Vpk + (size_t)(b * 4 + kvh) * 262144;

#define STAGE_TILE(ti, buf)                                                    \
  {                                                                            \
    const unsigned short* kg_ = Kg + (size_t)(ti) * 8192;                      \
    const unsigned short* vg_ = Vg + (size_t)(ti) * 8192;                      \
    _Pragma("unroll")                                                          \
    for (int i_ = 0; i_ < 4; i_++) {                                           \
      int seg_ = i_ * 4 + w;                                                   \
      async16(kg_ + (size_t)(seg_ * 64 + l) * 8, &Ks[buf][seg_ * 512]);        \
      async16(vg_ + (size_t)(seg_ * 64 + l) * 8, &Vs[buf][seg_ * 512]);        \
    }                                                                          \
  }

  for (int phase = 0; phase < 2; phase++) {
    const int strip = phase ? pj : (63 - pj);
    const int q0w = strip * 32;
    const int qg = q0w + q31;
    const unsigned short* Qs =
        Qpk + (((size_t)bh * 64 + strip) * 4096) + (size_t)l * 8;

    bf16x8 qf[8];
#pragma unroll
    for (int mf = 0; mf < 8; mf++)
      qf[mf] = ldfrag(Qs + mf * 512);
    asm volatile("s_waitcnt vmcnt(0)" ::: "memory");  // Q landed: keep vmcnt bookkeeping exact

    STAGE_TILE(0, 0);

    f32x16 o[4];
#pragma unroll
    for (int n = 0; n < 4; n++) o[n] = zero16();
    float m = -3.0e38f, lsum = 0.f;

    const int nt = (q0w + 95) >> 6;
    for (int ti = 0; ti < nt; ti++) {
      const int cur = ti & 1;
      const int kv0 = ti << 6;
      if (ti + 1 < nt) {
        STAGE_TILE(ti + 1, cur ^ 1);
        asm volatile("s_waitcnt vmcnt(8)" ::: "memory");  // cur tile landed; next in flight
      } else {
        asm volatile("s_waitcnt vmcnt(0)" ::: "memory");
      }
      __builtin_amdgcn_s_barrier();
      __builtin_amdgcn_sched_barrier(0);

      // ---- QK^T (swapped): A=K fragments, B=Q fragments, from LDS ----
      f32x16 s0 = zero16(), s1 = zero16();
      const unsigned short* kt = &Ks[cur][0];
      __builtin_amdgcn_s_setprio(1);
#pragma unroll
      for (int mf = 0; mf < 8; mf++) {
        s0 = mfma32(ldfrag(kt + mf * 512 + l * 8), qf[mf], s0);
        s1 = mfma32(ldfrag(kt + 4096 + mf * 512 + l * 8), qf[mf], s1);
      }
      __builtin_amdgcn_s_setprio(0);
      // ---- causal mask (last tile only) ----
      if (ti == nt - 1) {
        const int kvb = kv0 + 4 * hi;
#pragma unroll
        for (int r = 0; r < 16; r++) {
          int kv = kvb + (r & 3) + 8 * (r >> 2);
          if (kv > qg) s0[r] = -3.0e38f;
          if (kv + 32 > qg) s1[r] = -3.0e38f;
        }
      }
      // ---- online softmax, lane-local row (exp2 units) ----
      float pm = s0[0];
#pragma unroll
      for (int r = 1; r < 16; r++) pm = fmaxf(pm, s0[r]);
#pragma unroll
      for (int r = 0; r < 16; r++) pm = fmaxf(pm, s1[r]);
      pm = fmaxf(pm, __shfl_xor(pm, 32));
      if (__any(pm > m + 8.0f)) {          // defer-max: skip rescale when bounded
        float mn = fmaxf(m, pm);
        float scl = exp2f(m - mn);
        m = mn;
        lsum *= scl;
#pragma unroll
        for (int r = 0; r < 16; r++) {
          float sr = __shfl(scl, (r & 3) + 8 * (r >> 2) + 4 * hi);
          o[0][r] *= sr; o[1][r] *= sr; o[2][r] *= sr; o[3][r] *= sr;
        }
      }
#pragma unroll
      for (int r = 0; r < 16; r++) {
        s0[r] = exp2f(s0[r] - m);
        s1[r] = exp2f(s1[r] - m);
      }
      float ts = 0.f;
#pragma unroll
      for (int r = 0; r < 16; r++) ts += s0[r] + s1[r];
      ts += __shfl_xor(ts, 32);
      lsum += ts;
      // ---- pack P -> A-operand fragments (v_cvt_pk + register exchange) ----
      bf16x8 paf[4];
#pragma unroll
      for (int blk = 0; blk < 2; blk++) {
        f32x16& sx = blk ? s1 : s0;
#pragma unroll
        for (int blk2 = 0; blk2 < 2; blk2++) {
          const int base = 8 * blk2;
          unsigned g00 = cvtpk(sx[base + 0], sx[base + 1]);
          unsigned g01 = cvtpk(sx[base + 2], sx[base + 3]);
          unsigned g10 = cvtpk(sx[base + 4], sx[base + 5]);
          unsigned g11 = cvtpk(sx[base + 6], sx[base + 7]);
          unsigned snd0 = hi ? g00 : g10;   // partner needs regs indexed by ITS hi
          unsigned snd1 = hi ? g01 : g11;
          unsigned r0 = (unsigned)__shfl_xor((int)snd0, 32);
          unsigned r1 = (unsigned)__shfl_xor((int)snd1, 32);
          unsigned own0 = hi ? g10 : g00;
          unsigned own1 = hi ? g11 : g01;
          u32x4 wv;
          wv.x = hi ? r0 : own0;
          wv.y = hi ? r1 : own1;
          wv.z = hi ? own0 : r0;
          wv.w = hi ? own1 : r1;
          paf[blk * 2 + blk2] = __builtin_bit_cast(bf16x8, wv);
        }
      }
      // ---- PV: O[q][d] += P * V, V fragments from LDS ----
      const unsigned short* vt = &Vs[cur][0];
      __builtin_amdgcn_s_setprio(1);
#pragma unroll
      for (int n = 0; n < 4; n++) {
#pragma unroll
        for (int ks = 0; ks < 4; ks++)
          o[n] = mfma32(paf[ks], ldfrag(vt + (n * 4 + ks) * 512 + l * 8), o[n]);
      }
      __builtin_amdgcn_s_setprio(0);

      __builtin_amdgcn_sched_barrier(0);
      __builtin_amdgcn_s_barrier();   // all waves done reading buf[cur] before restage
    }
    // ---- epilogue: normalize rows, store ----
    float linv = 1.0f / lsum;
#pragma unroll
    for (int r = 0; r < 16; r++) {
      int cr = (r & 3) + 8 * (r >> 2) + 4 * hi;
      float lr = __shfl(linv, cr);
      int qrow = q0w + cr;
      size_t rowoff = ((size_t)(b * S_LEN + qrow)) * 2048 + h * 128 + q31;
      Y[rowoff]      = f2bf(o[0][r] * lr);
      Y[rowoff + 32] = f2bf(o[1][r] * lr);
      Y[rowoff + 64] = f2bf(o[2][r] * lr);
      Y[rowoff + 96] = f2bf(o[3][r] * lr);
    }
  }
#undef STAGE_TILE
}

// ---------------- launch ----------------
extern "C" void kernel_launch(void* const* d_in, const int* in_sizes, int n_in,
                              void* d_out, int out_size, void* d_ws, size_t ws_size,
                              hipStream_t stream) {
  const float* x  = (const float*)d_in[0];
  const float* rc = (const float*)d_in[1];
  const float* rs = (const float*)d_in[2];
  const float* Wq = (const float*)d_in[3];
  const float* Wk = (const float*)d_in[4];
  const float* Wv = (const float*)d_in[5];
  const float* Wo = (const float*)d_in[6];
  const float* qw = (const float*)d_in[7];
  const float* kw = (const float*)d_in[8];
  float* out = (float*)d_out;
  char* ws = (char*)d_ws;

  unsigned short* xb   = (unsigned short*)(ws + 0);
  unsigned short* WT   = (unsigned short*)(ws + 16777216);
  unsigned short* WoT  = (unsigned short*)(ws + 29360128);
  unsigned short* QKVb = (unsigned short*)(ws + 37748736);
  unsigned short* Qpk  = (unsigned short*)(ws + 0);          // over xb (dead)
  unsigned short* Kpk  = (unsigned short*)(ws + 16777216);   // over WT (dead)
  unsigned short* Vpk  = (unsigned short*)(ws + 20971520);   // over WT (dead)
  unsigned short* Yb   = (unsigned short*)(ws + 37748736);   // over QKVb (dead)

  cast_x_kernel<<<4096, 256, 0, stream>>>(x, xb, 1048576);
  transpose_cast_kernel<<<dim3(32, 32), 256, 0, stream>>>(Wq, WT, 2048, 2048, 0, 2048);
  transpose_cast_kernel<<<dim3(8, 32), 256, 0, stream>>>(Wk, WT, 2048, 512, 2048, 2048);
  transpose_cast_kernel<<<dim3(8, 32), 256, 0, stream>>>(Wv, WT, 2048, 512, 2560, 2048);
  transpose_cast_kernel<<<dim3(32, 32), 256, 0, stream>>>(Wo, WoT, 2048, 2048, 0, 2048);
  gemm_bf16_kernel<<<dim3(24, 32), 256, 0, stream>>>(xb, WT, QKVb, 4096, 3072, 2048, 1);
  mid_kernel<<<24576, 256, 0, stream>>>(QKVb, rc, rs, qw, kw, Qpk, Kpk, Vpk);
  attn_kernel<<<256, 256, 0, stream>>>(Qpk, Kpk, Vpk, Yb);
  gemm_bf16_kernel<<<dim3(16, 32), 256, 0, stream>>>(Yb, WoT, out, 4096, 2048, 2048, 0);
}

// Round 8
// 242.200 us; speedup vs baseline: 1.1788x; 1.0905x over previous
//
#include <hip/hip_runtime.h>

// CausalSelfAttention: B=2,S=2048,H=2048,NH=16,NKV=4,HD=128, fp32 in/out,
// internal bf16 MFMA pipeline.
// Round 8: (a) attn processes 2 KV tiles per barrier round (128KB LDS dbuf,
// vmcnt(16)) -- r7 showed ~7.85K cyc/tile vs ~2K floor with a large FIXED
// per-round cost (barriers+vmcnt+latency at 1 wave/SIMD); amortize it 2x.
// (b) GEMMs converted to counted-vmcnt 2-phase dbuf pipeline (T3/T4 minimum
// recipe, r5-proven structure): stage(t+1) -> vmcnt(4) -> barrier -> MFMA.
// ws layout (bytes):
//   [0,16.8M)      xb (x cast bf16)          -> reused later: Qpk (16MB)
//   [16.8M,29.4M)  WqkvT bf16 [3072][2048]   -> reused later: Kpk(4MB)+Vpk(4MB)
//   [29.4M,37.7M)  WoT bf16 [2048][2048]
//   [37.7M,62.9M)  QKVb bf16 [4096][3072]    -> reused later: Y bf16 [4096][2048]

#define S_LEN 2048

typedef __bf16 bf16_t;
typedef bf16_t bf16x8 __attribute__((ext_vector_type(8)));
typedef float f32x4 __attribute__((ext_vector_type(4)));
typedef float f32x16 __attribute__((ext_vector_type(16)));
typedef unsigned int u32x4 __attribute__((ext_vector_type(4)));
typedef unsigned short u16x4 __attribute__((ext_vector_type(4)));

__device__ __forceinline__ unsigned short f2bf(float f) {
  unsigned int u = __builtin_bit_cast(unsigned int, f);
  u += 0x7fffu + ((u >> 16) & 1u);
  return (unsigned short)(u >> 16);
}
__device__ __forceinline__ float bf2f(unsigned short h) {
  return __builtin_bit_cast(float, (unsigned int)h << 16);
}
__device__ __forceinline__ unsigned pk2(float a, float b) {
  return (unsigned)f2bf(a) | ((unsigned)f2bf(b) << 16);
}
// HW packed convert: lo = bf16(a), hi = bf16(b). Single VALU instruction.
__device__ __forceinline__ unsigned cvtpk(float a, float b) {
  unsigned r;
  asm("v_cvt_pk_bf16_f32 %0, %1, %2" : "=v"(r) : "v"(a), "v"(b));
  return r;
}

typedef const __attribute__((address_space(1))) unsigned int* gas1_t;
typedef __attribute__((address_space(3))) unsigned int* las3_t;
__device__ __forceinline__ void async16(const void* g, void* l) {
  __builtin_amdgcn_global_load_lds((gas1_t)g, (las3_t)l, 16, 0, 0);
}

__device__ __forceinline__ bf16x8 ldfrag(const void* p) {
  return __builtin_bit_cast(bf16x8, *(const u32x4*)p);
}
__device__ __forceinline__ f32x16 mfma32(bf16x8 a, bf16x8 b, f32x16 c) {
  return __builtin_amdgcn_mfma_f32_32x32x16_bf16(a, b, c, 0, 0, 0);
}
__device__ __forceinline__ f32x16 zero16() {
  f32x16 v;
#pragma unroll
  for (int i = 0; i < 16; i++) v[i] = 0.f;
  return v;
}

// ---------------- cast x fp32 -> bf16 ----------------
__global__ __launch_bounds__(256) void cast_x_kernel(
    const float* __restrict__ in, unsigned short* __restrict__ out, int n8) {
  int i = blockIdx.x * 256 + threadIdx.x;
  if (i >= n8) return;
  const f32x4* p = (const f32x4*)in + (size_t)i * 2;
  f32x4 a = p[0], b = p[1];
  u32x4 o;
  o.x = pk2(a.x, a.y);
  o.y = pk2(a.z, a.w);
  o.z = pk2(b.x, b.y);
  o.w = pk2(b.z, b.w);
  *(u32x4*)(out + (size_t)i * 8) = o;
}

// ---------------- transpose+cast: in fp32 [R][C] -> out bf16 [C][R] ----------------
__global__ __launch_bounds__(256) void transpose_cast_kernel(
    const float* __restrict__ in, unsigned short* __restrict__ out,
    int R, int C, int out_row_off, int out_ld) {
  __shared__ unsigned short L[64][68];
  int t = threadIdx.x;
  int r0 = blockIdx.y * 64, c0 = blockIdx.x * 64;
#pragma unroll
  for (int i = 0; i < 4; i++) {
    int r = i * 16 + (t >> 4);
    int c = (t & 15) * 4;
    f32x4 v = *(const f32x4*)&in[(size_t)(r0 + r) * C + c0 + c];
    u16x4 u;
    u.x = f2bf(v.x); u.y = f2bf(v.y); u.z = f2bf(v.z); u.w = f2bf(v.w);
    *(u16x4*)&L[r][c] = u;
  }
  __syncthreads();
#pragma unroll
  for (int i = 0; i < 4; i++) {
    int oc = i * 16 + (t >> 4);
    int orr = (t & 15) * 4;
    u16x4 u;
    u.x = L[orr + 0][oc]; u.y = L[orr + 1][oc];
    u.z = L[orr + 2][oc]; u.w = L[orr + 3][oc];
    *(u16x4*)&out[(size_t)(c0 + oc + out_row_off) * out_ld + r0 + orr] = u;
  }
}

// ---------------- bf16 GEMM: C[M][N] = A[M][K] * Bt[N][K]^T ----------------
// 128x128 tile, BK=32, dbuf LDS + counted vmcnt(4) pipeline (T3/T4 minimum).
__global__ __launch_bounds__(256) void gemm_bf16_kernel(
    const unsigned short* __restrict__ A, const unsigned short* __restrict__ Bt,
    void* __restrict__ Cout, int M, int N, int K, int out_bf16) {
  __shared__ unsigned short As[2][128 * 32];
  __shared__ unsigned short Bs[2][128 * 32];
  const int t = threadIdx.x, w = t >> 6, l = t & 63;
  const int wr = w >> 1, wc = w & 1;
  const int lrow = l & 15, lhi = l >> 4;
  const int row0 = blockIdx.y * 128, col0 = blockIdx.x * 128;
  const unsigned short* Ab = A + (size_t)row0 * K;
  const unsigned short* Bb = Bt + (size_t)col0 * K;
  const int srow = w * 32 + (l >> 2);
  const int scol = (l & 3) * 8;
  f32x4 z = {0.f, 0.f, 0.f, 0.f};
  f32x4 acc[4][4];
#pragma unroll
  for (int m = 0; m < 4; m++)
#pragma unroll
    for (int n = 0; n < 4; n++) acc[m][n] = z;

#define STAGE_G(tt, buf)                                                        \
  {                                                                             \
    const int k0_ = (tt) * 32;                                                  \
    async16(Ab + (size_t)srow * K + k0_ + scol,        &As[buf][(w * 32) * 32]);\
    async16(Ab + (size_t)(srow + 16) * K + k0_ + scol, &As[buf][(w * 32 + 16) * 32]); \
    async16(Bb + (size_t)srow * K + k0_ + scol,        &Bs[buf][(w * 32) * 32]);\
    async16(Bb + (size_t)(srow + 16) * K + k0_ + scol, &Bs[buf][(w * 32 + 16) * 32]); \
  }

  STAGE_G(0, 0);
  const int NT = K >> 5;
  for (int tt = 0; tt < NT; tt++) {
    const int cur = tt & 1;
    if (tt + 1 < NT) {
      STAGE_G(tt + 1, cur ^ 1);
      asm volatile("s_waitcnt vmcnt(4)" ::: "memory");  // tile tt landed; tt+1 in flight
    } else {
      asm volatile("s_waitcnt vmcnt(0)" ::: "memory");
    }
    __builtin_amdgcn_s_barrier();
    __builtin_amdgcn_sched_barrier(0);
    bf16x8 af[4], bfr[4];
#pragma unroll
    for (int m = 0; m < 4; m++)
      af[m] = ldfrag(&As[cur][(wr * 64 + m * 16 + lrow) * 32 + lhi * 8]);
#pragma unroll
    for (int n = 0; n < 4; n++)
      bfr[n] = ldfrag(&Bs[cur][(wc * 64 + n * 16 + lrow) * 32 + lhi * 8]);
    __builtin_amdgcn_s_setprio(1);
#pragma unroll
    for (int m = 0; m < 4; m++)
#pragma unroll
      for (int n = 0; n < 4; n++)
        acc[m][n] = __builtin_amdgcn_mfma_f32_16x16x32_bf16(af[m], bfr[n], acc[m][n], 0, 0, 0);
    __builtin_amdgcn_s_setprio(0);
    __builtin_amdgcn_sched_barrier(0);
    __builtin_amdgcn_s_barrier();   // all waves done reading buf[cur] before restage
  }
#undef STAGE_G

  if (out_bf16) {
    unsigned short* C = (unsigned short*)Cout;
#pragma unroll
    for (int m = 0; m < 4; m++)
#pragma unroll
      for (int n = 0; n < 4; n++)
#pragma unroll
        for (int r = 0; r < 4; r++) {
          size_t grow = row0 + wr * 64 + m * 16 + lhi * 4 + r;
          size_t gcol = col0 + wc * 64 + n * 16 + lrow;
          C[grow * N + gcol] = f2bf(acc[m][n][r]);
        }
  } else {
    float* C = (float*)Cout;
#pragma unroll
    for (int m = 0; m < 4; m++)
#pragma unroll
      for (int n = 0; n < 4; n++)
#pragma unroll
        for (int r = 0; r < 4; r++) {
          size_t grow = row0 + wr * 64 + m * 16 + lhi * 4 + r;
          size_t gcol = col0 + wc * 64 + n * 16 + lrow;
          C[grow * N + gcol] = acc[m][n][r];
        }
  }
}

// ---------------- mid: RMSNorm + RoPE, write fragment-packed Q/K/V ----------------
// Packed layouts (all fragment loads in attn become base + lane*16B):
//  Qpk[bh][strip=s/32][mf 0..7][hi 0..1][q31=s%32][j 0..7]   (4096 elems/strip)
//  Kpk[b*4+kvh][blk=s/32][mf][hi][kv31=s%32][j]              (4096 elems/blk)
//  Vpk[b*4+kvh][kv0=s/64][n 0..3][ks 0..3][hi=(s%16)/8][d31=d%32][j=s%8]
//                                                            (8192 elems/tile)
// Q gets (1/sqrt(128))*log2(e) baked in (attention works in exp2 units).
__global__ __launch_bounds__(256) void mid_kernel(
    const unsigned short* __restrict__ QKV, const float* __restrict__ cosT,
    const float* __restrict__ sinT, const float* __restrict__ qw,
    const float* __restrict__ kw, unsigned short* __restrict__ Qpk,
    unsigned short* __restrict__ Kpk, unsigned short* __restrict__ Vpk) {
  int w = threadIdx.x >> 6, l = threadIdx.x & 63;
  int g = blockIdx.x * 4 + w;
  int bs = g / 24, idx = g - bs * 24;
  int b = bs >> 11, s = bs & 2047;
  int d0 = 2 * l;
  unsigned int uu = *(const unsigned int*)(QKV + (size_t)bs * 3072 + idx * 128 + d0);
  float x0 = bf2f((unsigned short)(uu & 0xffffu));
  float x1 = bf2f((unsigned short)(uu >> 16));
  if (idx < 20) {
    const float* nw = (idx < 16) ? qw : kw;
    float ss = x0 * x0 + x1 * x1;
#pragma unroll
    for (int mk = 1; mk < 64; mk <<= 1) ss += __shfl_xor(ss, mk);
    float inv = rsqrtf(ss * (1.0f / 128.0f) + 1e-6f);
    float n0 = x0 * inv * nw[d0], n1 = x1 * inv * nw[d0 + 1];
    float p0 = __shfl_xor(n0, 32), p1 = __shfl_xor(n1, 32);
    float sg = (l < 32) ? -1.0f : 1.0f;
    float c0 = cosT[s * 128 + d0], c1 = cosT[s * 128 + d0 + 1];
    float sn0 = sinT[s * 128 + d0], sn1 = sinT[s * 128 + d0 + 1];
    float o0 = n0 * c0 + sg * p0 * sn0;
    float o1 = n1 * c1 + sg * p1 * sn1;
    int mf = d0 >> 4, hi = (d0 >> 3) & 1, j = d0 & 7;
    int blk = s >> 5, r31 = s & 31;
    int foff = (mf * 2 + hi) * 256 + r31 * 8 + j;
    unsigned short* dst;
    if (idx < 16) {
      const float qs = 0.08838834764831845f * 1.4426950408889634f;  // 1/sqrt(128)*log2e
      o0 *= qs; o1 *= qs;
      dst = Qpk + (((size_t)(b * 16 + idx)) * 64 + blk) * 4096 + foff;
    } else {
      dst = Kpk + (((size_t)(b * 4 + (idx - 16))) * 64 + blk) * 4096 + foff;
    }
    *(unsigned int*)dst = pk2(o0, o1);
  } else {
    int kvh = idx - 20;
    int kv0 = s >> 6, ks = (s >> 4) & 3, his = (s >> 3) & 1, j = s & 7;
    int n = d0 >> 5, d31 = d0 & 31;
    size_t base = (((size_t)(b * 4 + kvh)) * 32 + kv0) * 8192 +
                  (((n * 4 + ks) * 2 + his) * 256 + d31 * 8 + j);
    Vpk[base] = f2bf(x0);
    Vpk[base + 8] = f2bf(x1);   // d0+1 -> d31+1
  }
}

// ---------------- flash attention: async-LDS pipeline, 2 KV tiles / round ----------------
// 256 equal-work blocks x 4 waves. Block = (b,kvh,pj); wave w = head kvh*4+w.
// bid&7 -> (b,kvh) (XCD-pinned K/V). Block runs strip 63-pj then strip pj
// sequentially (nt sum == 33 for every block). Per ROUND: stage TWO KV tiles
// (2x 16KB K + 2x 16KB V) into a 128KB double buffer; vmcnt(16) keeps next
// round's stage in flight across the raw s_barrier. Amortizes the measured
// ~5K-cycle fixed per-round cost (r7: 7.85K cyc/tile vs ~2K work floor).
__global__ __launch_bounds__(256) void attn_kernel(
    const unsigned short* __restrict__ Qpk, const unsigned short* __restrict__ Kpk,
    const unsigned short* __restrict__ Vpk, unsigned short* __restrict__ Y) {
  __shared__ unsigned short Ks[2][2][8192];   // [dbuf][subtile][frag data]
  __shared__ unsigned short Vs[2][2][8192];
  const int w = threadIdx.x >> 6, l = threadIdx.x & 63;
  const int q31 = l & 31, hi = l >> 5;
  const int bid = blockIdx.x;
  const int xcd = bid & 7;
  const int b = xcd >> 2, kvh = xcd & 3;
  const int h = kvh * 4 + w;
  const int bh = b * 16 + h;
  const int pj = bid >> 3;             // 0..31
  const unsigned short* Kg = Kpk + (size_t)(b * 4 + kvh) * 262144;
  const unsigned short* Vg = Vpk + (size_t)(b * 4 + kvh) * 262144;

#define STAGE_SUB(ti, buf, sub)                                                \
  {                                                                            \
    const unsigned short* kg_ = Kg + (size_t)(ti) * 8192;                      \
    const unsigned short* vg_ = Vg + (size_t)(ti) * 8192;                      \
    _Pragma("unroll")                                                          \
    for (int i_ = 0; i_ < 4; i_++) {                                           \
      int seg_ = i_ * 4 + w;                                                   \
      async16(kg_ + (size_t)(seg_ * 64 + l) * 8, &Ks[buf][sub][seg_ * 512]);   \
      async16(vg_ + (size_t)(seg_ * 64 + l) * 8, &Vs[buf][sub][seg_ * 512]);   \
    }                                                                          \
  }

  for (int phase = 0; phase < 2; phase++) {
    const int strip = phase ? pj : (63 - pj);
    const int q0w = strip * 32;
    const int qg = q0w + q31;
    const unsigned short* Qs =
        Qpk + (((size_t)bh * 64 + strip) * 4096) + (size_t)l * 8;

    bf16x8 qf[8];
#pragma unroll
    for (int mf = 0; mf < 8; mf++)
      qf[mf] = ldfrag(Qs + mf * 512);
    asm volatile("s_waitcnt vmcnt(0)" ::: "memory");  // Q landed: exact vmcnt bookkeeping

    const int nt = (q0w + 95) >> 6;          // 1..32 KV tiles
    const int nr = (nt + 1) >> 1;            // rounds of 2 tiles
    STAGE_SUB(0, 0, 0);
    STAGE_SUB((nt > 1 ? 1 : 0), 0, 1);

    f32x16 o[4];
#pragma unroll
    for (int n = 0; n < 4; n++) o[n] = zero16();
    float m = -3.0e38f, lsum = 0.f;

    for (int r = 0; r < nr; r++) {
      const int cur = r & 1;
      if (r + 1 < nr) {
        const int t0 = 2 * r + 2;
        const int t1 = (2 * r + 3 < nt) ? (2 * r + 3) : (nt - 1);
        STAGE_SUB(t0, cur ^ 1, 0);
        STAGE_SUB(t1, cur ^ 1, 1);
        asm volatile("s_waitcnt vmcnt(16)" ::: "memory");  // this round landed; next in flight
      } else {
        asm volatile("s_waitcnt vmcnt(0)" ::: "memory");
      }
      __builtin_amdgcn_s_barrier();
      __builtin_amdgcn_sched_barrier(0);

#pragma unroll
      for (int sub = 0; sub < 2; sub++) {
        const int ti = 2 * r + sub;
        if (ti < nt) {
          const int kv0 = ti << 6;
          // ---- QK^T (swapped): A=K fragments, B=Q fragments, from LDS ----
          f32x16 s0 = zero16(), s1 = zero16();
          const unsigned short* kt = &Ks[cur][sub][0];
          __builtin_amdgcn_s_setprio(1);
#pragma unroll
          for (int mf = 0; mf < 8; mf++) {
            s0 = mfma32(ldfrag(kt + mf * 512 + l * 8), qf[mf], s0);
            s1 = mfma32(ldfrag(kt + 4096 + mf * 512 + l * 8), qf[mf], s1);
          }
          __builtin_amdgcn_s_setprio(0);
          // ---- causal mask (last tile only) ----
          if (ti == nt - 1) {
            const int kvb = kv0 + 4 * hi;
#pragma unroll
            for (int rr = 0; rr < 16; rr++) {
              int kv = kvb + (rr & 3) + 8 * (rr >> 2);
              if (kv > qg) s0[rr] = -3.0e38f;
              if (kv + 32 > qg) s1[rr] = -3.0e38f;
            }
          }
          // ---- online softmax, lane-local row (exp2 units) ----
          float pm = s0[0];
#pragma unroll
          for (int rr = 1; rr < 16; rr++) pm = fmaxf(pm, s0[rr]);
#pragma unroll
          for (int rr = 0; rr < 16; rr++) pm = fmaxf(pm, s1[rr]);
          pm = fmaxf(pm, __shfl_xor(pm, 32));
          if (__any(pm > m + 8.0f)) {      // defer-max: skip rescale when bounded
            float mn = fmaxf(m, pm);
            float scl = exp2f(m - mn);
            m = mn;
            lsum *= scl;
#pragma unroll
            for (int rr = 0; rr < 16; rr++) {
              float sr = __shfl(scl, (rr & 3) + 8 * (rr >> 2) + 4 * hi);
              o[0][rr] *= sr; o[1][rr] *= sr; o[2][rr] *= sr; o[3][rr] *= sr;
            }
          }
#pragma unroll
          for (int rr = 0; rr < 16; rr++) {
            s0[rr] = exp2f(s0[rr] - m);
            s1[rr] = exp2f(s1[rr] - m);
          }
          float ts = 0.f;
#pragma unroll
          for (int rr = 0; rr < 16; rr++) ts += s0[rr] + s1[rr];
          ts += __shfl_xor(ts, 32);
          lsum += ts;
          // ---- pack P -> A-operand fragments (v_cvt_pk + register exchange) ----
          bf16x8 paf[4];
#pragma unroll
          for (int blk = 0; blk < 2; blk++) {
            f32x16& sx = blk ? s1 : s0;
#pragma unroll
            for (int blk2 = 0; blk2 < 2; blk2++) {
              const int base = 8 * blk2;
              unsigned g00 = cvtpk(sx[base + 0], sx[base + 1]);
              unsigned g01 = cvtpk(sx[base + 2], sx[base + 3]);
              unsigned g10 = cvtpk(sx[base + 4], sx[base + 5]);
              unsigned g11 = cvtpk(sx[base + 6], sx[base + 7]);
              unsigned snd0 = hi ? g00 : g10;   // partner needs regs indexed by ITS hi
              unsigned snd1 = hi ? g01 : g11;
              unsigned r0 = (unsigned)__shfl_xor((int)snd0, 32);
              unsigned r1 = (unsigned)__shfl_xor((int)snd1, 32);
              unsigned own0 = hi ? g10 : g00;
              unsigned own1 = hi ? g11 : g01;
              u32x4 wv;
              wv.x = hi ? r0 : own0;
              wv.y = hi ? r1 : own1;
              wv.z = hi ? own0 : r0;
              wv.w = hi ? own1 : r1;
              paf[blk * 2 + blk2] = __builtin_bit_cast(bf16x8, wv);
            }
          }
          // ---- PV: O[q][d] += P * V, V fragments from LDS ----
          const unsigned short* vt = &Vs[cur][sub][0];
          __builtin_amdgcn_s_setprio(1);
#pragma unroll
          for (int n = 0; n < 4; n++) {
#pragma unroll
            for (int ks = 0; ks < 4; ks++)
              o[n] = mfma32(paf[ks], ldfrag(vt + (n * 4 + ks) * 512 + l * 8), o[n]);
          }
          __builtin_amdgcn_s_setprio(0);
        }
      }

      __builtin_amdgcn_sched_barrier(0);
      __builtin_amdgcn_s_barrier();   // all waves done reading buf[cur] before restage
    }
    // ---- epilogue: normalize rows, store ----
    float linv = 1.0f / lsum;
#pragma unroll
    for (int rr = 0; rr < 16; rr++) {
      int cr = (rr & 3) + 8 * (rr >> 2) + 4 * hi;
      float lr = __shfl(linv, cr);
      int qrow = q0w + cr;
      size_t rowoff = ((size_t)(b * S_LEN + qrow)) * 2048 + h * 128 + q31;
      Y[rowoff]      = f2bf(o[0][rr] * lr);
      Y[rowoff + 32] = f2bf(o[1][rr] * lr);
      Y[rowoff + 64] = f2bf(o[2][rr] * lr);
      Y[rowoff + 96] = f2bf(o[3][rr] * lr);
    }
  }
#undef STAGE_SUB
}

// ---------------- launch ----------------
extern "C" void kernel_launch(void* const* d_in, const int* in_sizes, int n_in,
                              void* d_out, int out_size, void* d_ws, size_t ws_size,
                              hipStream_t stream) {
  const float* x  = (const float*)d_in[0];
  const float* rc = (const float*)d_in[1];
  const float* rs = (const float*)d_in[2];
  const float* Wq = (const float*)d_in[3];
  const float* Wk = (const float*)d_in[4];
  const float* Wv = (const float*)d_in[5];
  const float* Wo = (const float*)d_in[6];
  const float* qw = (const float*)d_in[7];
  const float* kw = (const float*)d_in[8];
  float* out = (float*)d_out;
  char* ws = (char*)d_ws;

  unsigned short* xb   = (unsigned short*)(ws + 0);
  unsigned short* WT   = (unsigned short*)(ws + 16777216);
  unsigned short* WoT  = (unsigned short*)(ws + 29360128);
  unsigned short* QKVb = (unsigned short*)(ws + 37748736);
  unsigned short* Qpk  = (unsigned short*)(ws + 0);          // over xb (dead)
  unsigned short* Kpk  = (unsigned short*)(ws + 16777216);   // over WT (dead)
  unsigned short* Vpk  = (unsigned short*)(ws + 20971520);   // over WT (dead)
  unsigned short* Yb   = (unsigned short*)(ws + 37748736);   // over QKVb (dead)

  cast_x_kernel<<<4096, 256, 0, stream>>>(x, xb, 1048576);
  transpose_cast_kernel<<<dim3(32, 32), 256, 0, stream>>>(Wq, WT, 2048, 2048, 0, 2048);
  transpose_cast_kernel<<<dim3(8, 32), 256, 0, stream>>>(Wk, WT, 2048, 512, 2048, 2048);
  transpose_cast_kernel<<<dim3(8, 32), 256, 0, stream>>>(Wv, WT, 2048, 512, 2560, 2048);
  transpose_cast_kernel<<<dim3(32, 32), 256, 0, stream>>>(Wo, WoT, 2048, 2048, 0, 2048);
  gemm_bf16_kernel<<<dim3(24, 32), 256, 0, stream>>>(xb, WT, QKVb, 4096, 3072, 2048, 1);
  mid_kernel<<<24576, 256, 0, stream>>>(QKVb, rc, rs, qw, kw, Qpk, Kpk, Vpk);
  attn_kernel<<<256, 256, 0, stream>>>(Qpk, Kpk, Vpk, Yb);
  gemm_bf16_kernel<<<dim3(16, 32), 256, 0, stream>>>(Yb, WoT, out, 4096, 2048, 2048, 0);
}

// Round 10
// 224.857 us; speedup vs baseline: 1.2698x; 1.0771x over previous
//
#include <hip/hip_runtime.h>

// CausalSelfAttention: B=2,S=2048,H=2048,NH=16,NKV=4,HD=128, fp32 in/out,
// internal bf16 MFMA pipeline.
// Round 10 = Round 9 structure with two epilogue bugs fixed:
//  (1) mlb was at lds_raw+96K == one byte past the 96K array -> OOB LDS.
//      lds_raw now 100352 B; mlb in-bounds at offset 98304.
//  (2) epilogue m/l/O exchange used raw s_barrier (no lgkmcnt drain) ->
//      cross-wave ds_write visibility race. Epilogue now uses __syncthreads().
// Structure: 8-wave blocks, KV-split across two wave-groups, in-LDS flash
// combine, KVBLK=32, triple-buffered staging w/ one barrier per round,
// equal-work blocks. GEMMs keep r8's counted-vmcnt pipeline.
// ws layout (bytes):
//   [0,16.8M)      xb (x cast bf16)          -> reused later: Qpk (16MB)
//   [16.8M,29.4M)  WqkvT bf16 [3072][2048]   -> reused later: Kpk(4MB)+Vpk(4MB)
//   [29.4M,37.7M)  WoT bf16 [2048][2048]
//   [37.7M,62.9M)  QKVb bf16 [4096][3072]    -> reused later: Y bf16 [4096][2048]

#define S_LEN 2048

typedef __bf16 bf16_t;
typedef bf16_t bf16x8 __attribute__((ext_vector_type(8)));
typedef float f32x4 __attribute__((ext_vector_type(4)));
typedef float f32x16 __attribute__((ext_vector_type(16)));
typedef unsigned int u32x4 __attribute__((ext_vector_type(4)));
typedef unsigned short u16x4 __attribute__((ext_vector_type(4)));

__device__ __forceinline__ unsigned short f2bf(float f) {
  unsigned int u = __builtin_bit_cast(unsigned int, f);
  u += 0x7fffu + ((u >> 16) & 1u);
  return (unsigned short)(u >> 16);
}
__device__ __forceinline__ float bf2f(unsigned short h) {
  return __builtin_bit_cast(float, (unsigned int)h << 16);
}
__device__ __forceinline__ unsigned pk2(float a, float b) {
  return (unsigned)f2bf(a) | ((unsigned)f2bf(b) << 16);
}
// HW packed convert: lo = bf16(a), hi = bf16(b). Single VALU instruction.
__device__ __forceinline__ unsigned cvtpk(float a, float b) {
  unsigned r;
  asm("v_cvt_pk_bf16_f32 %0, %1, %2" : "=v"(r) : "v"(a), "v"(b));
  return r;
}

typedef const __attribute__((address_space(1))) unsigned int* gas1_t;
typedef __attribute__((address_space(3))) unsigned int* las3_t;
__device__ __forceinline__ void async16(const void* g, void* l) {
  __builtin_amdgcn_global_load_lds((gas1_t)g, (las3_t)l, 16, 0, 0);
}

__device__ __forceinline__ bf16x8 ldfrag(const void* p) {
  return __builtin_bit_cast(bf16x8, *(const u32x4*)p);
}
__device__ __forceinline__ f32x16 mfma32(bf16x8 a, bf16x8 b, f32x16 c) {
  return __builtin_amdgcn_mfma_f32_32x32x16_bf16(a, b, c, 0, 0, 0);
}
__device__ __forceinline__ f32x16 zero16() {
  f32x16 v;
#pragma unroll
  for (int i = 0; i < 16; i++) v[i] = 0.f;
  return v;
}

// ---------------- cast x fp32 -> bf16 ----------------
__global__ __launch_bounds__(256) void cast_x_kernel(
    const float* __restrict__ in, unsigned short* __restrict__ out, int n8) {
  int i = blockIdx.x * 256 + threadIdx.x;
  if (i >= n8) return;
  const f32x4* p = (const f32x4*)in + (size_t)i * 2;
  f32x4 a = p[0], b = p[1];
  u32x4 o;
  o.x = pk2(a.x, a.y);
  o.y = pk2(a.z, a.w);
  o.z = pk2(b.x, b.y);
  o.w = pk2(b.z, b.w);
  *(u32x4*)(out + (size_t)i * 8) = o;
}

// ---------------- transpose+cast: in fp32 [R][C] -> out bf16 [C][R] ----------------
__global__ __launch_bounds__(256) void transpose_cast_kernel(
    const float* __restrict__ in, unsigned short* __restrict__ out,
    int R, int C, int out_row_off, int out_ld) {
  __shared__ unsigned short L[64][68];
  int t = threadIdx.x;
  int r0 = blockIdx.y * 64, c0 = blockIdx.x * 64;
#pragma unroll
  for (int i = 0; i < 4; i++) {
    int r = i * 16 + (t >> 4);
    int c = (t & 15) * 4;
    f32x4 v = *(const f32x4*)&in[(size_t)(r0 + r) * C + c0 + c];
    u16x4 u;
    u.x = f2bf(v.x); u.y = f2bf(v.y); u.z = f2bf(v.z); u.w = f2bf(v.w);
    *(u16x4*)&L[r][c] = u;
  }
  __syncthreads();
#pragma unroll
  for (int i = 0; i < 4; i++) {
    int oc = i * 16 + (t >> 4);
    int orr = (t & 15) * 4;
    u16x4 u;
    u.x = L[orr + 0][oc]; u.y = L[orr + 1][oc];
    u.z = L[orr + 2][oc]; u.w = L[orr + 3][oc];
    *(u16x4*)&out[(size_t)(c0 + oc + out_row_off) * out_ld + r0 + orr] = u;
  }
}

// ---------------- bf16 GEMM: C[M][N] = A[M][K] * Bt[N][K]^T ----------------
// 128x128 tile, BK=32, dbuf LDS + counted vmcnt(4) pipeline (r8, kept).
__global__ __launch_bounds__(256) void gemm_bf16_kernel(
    const unsigned short* __restrict__ A, const unsigned short* __restrict__ Bt,
    void* __restrict__ Cout, int M, int N, int K, int out_bf16) {
  __shared__ unsigned short As[2][128 * 32];
  __shared__ unsigned short Bs[2][128 * 32];
  const int t = threadIdx.x, w = t >> 6, l = t & 63;
  const int wr = w >> 1, wc = w & 1;
  const int lrow = l & 15, lhi = l >> 4;
  const int row0 = blockIdx.y * 128, col0 = blockIdx.x * 128;
  const unsigned short* Ab = A + (size_t)row0 * K;
  const unsigned short* Bb = Bt + (size_t)col0 * K;
  const int srow = w * 32 + (l >> 2);
  const int scol = (l & 3) * 8;
  f32x4 z = {0.f, 0.f, 0.f, 0.f};
  f32x4 acc[4][4];
#pragma unroll
  for (int m = 0; m < 4; m++)
#pragma unroll
    for (int n = 0; n < 4; n++) acc[m][n] = z;

#define STAGE_G(tt, buf)                                                        \
  {                                                                             \
    const int k0_ = (tt) * 32;                                                  \
    async16(Ab + (size_t)srow * K + k0_ + scol,        &As[buf][(w * 32) * 32]);\
    async16(Ab + (size_t)(srow + 16) * K + k0_ + scol, &As[buf][(w * 32 + 16) * 32]); \
    async16(Bb + (size_t)srow * K + k0_ + scol,        &Bs[buf][(w * 32) * 32]);\
    async16(Bb + (size_t)(srow + 16) * K + k0_ + scol, &Bs[buf][(w * 32 + 16) * 32]); \
  }

  STAGE_G(0, 0);
  const int NT = K >> 5;
  for (int tt = 0; tt < NT; tt++) {
    const int cur = tt & 1;
    if (tt + 1 < NT) {
      STAGE_G(tt + 1, cur ^ 1);
      asm volatile("s_waitcnt vmcnt(4)" ::: "memory");
    } else {
      asm volatile("s_waitcnt vmcnt(0)" ::: "memory");
    }
    __builtin_amdgcn_s_barrier();
    __builtin_amdgcn_sched_barrier(0);
    bf16x8 af[4], bfr[4];
#pragma unroll
    for (int m = 0; m < 4; m++)
      af[m] = ldfrag(&As[cur][(wr * 64 + m * 16 + lrow) * 32 + lhi * 8]);
#pragma unroll
    for (int n = 0; n < 4; n++)
      bfr[n] = ldfrag(&Bs[cur][(wc * 64 + n * 16 + lrow) * 32 + lhi * 8]);
    __builtin_amdgcn_s_setprio(1);
#pragma unroll
    for (int m = 0; m < 4; m++)
#pragma unroll
      for (int n = 0; n < 4; n++)
        acc[m][n] = __builtin_amdgcn_mfma_f32_16x16x32_bf16(af[m], bfr[n], acc[m][n], 0, 0, 0);
    __builtin_amdgcn_s_setprio(0);
    __builtin_amdgcn_sched_barrier(0);
    __builtin_amdgcn_s_barrier();
  }
#undef STAGE_G

  if (out_bf16) {
    unsigned short* C = (unsigned short*)Cout;
#pragma unroll
    for (int m = 0; m < 4; m++)
#pragma unroll
      for (int n = 0; n < 4; n++)
#pragma unroll
        for (int r = 0; r < 4; r++) {
          size_t grow = row0 + wr * 64 + m * 16 + lhi * 4 + r;
          size_t gcol = col0 + wc * 64 + n * 16 + lrow;
          C[grow * N + gcol] = f2bf(acc[m][n][r]);
        }
  } else {
    float* C = (float*)Cout;
#pragma unroll
    for (int m = 0; m < 4; m++)
#pragma unroll
      for (int n = 0; n < 4; n++)
#pragma unroll
        for (int r = 0; r < 4; r++) {
          size_t grow = row0 + wr * 64 + m * 16 + lhi * 4 + r;
          size_t gcol = col0 + wc * 64 + n * 16 + lrow;
          C[grow * N + gcol] = acc[m][n][r];
        }
  }
}

// ---------------- mid: RMSNorm + RoPE, write fragment-packed Q/K/V ----------------
// Packed layouts (all fragment loads in attn become base + lane*16B):
//  Qpk[bh][strip=s/32][mf 0..7][hi][q31][j]                  (4096 elems/strip)
//  Kpk[b*4+kvh][blk=s/32][mf][hi][kv31][j]                   (4096 elems/blk)
//  Vpk[b*4+kvh][blk=s/32][n 0..3][ks 0..1][his][d31][j=s&7]  (4096 elems/blk)
// Q gets (1/sqrt(128))*log2(e) baked in (attention works in exp2 units).
__global__ __launch_bounds__(256) void mid_kernel(
    const unsigned short* __restrict__ QKV, const float* __restrict__ cosT,
    const float* __restrict__ sinT, const float* __restrict__ qw,
    const float* __restrict__ kw, unsigned short* __restrict__ Qpk,
    unsigned short* __restrict__ Kpk, unsigned short* __restrict__ Vpk) {
  int w = threadIdx.x >> 6, l = threadIdx.x & 63;
  int g = blockIdx.x * 4 + w;
  int bs = g / 24, idx = g - bs * 24;
  int b = bs >> 11, s = bs & 2047;
  int d0 = 2 * l;
  unsigned int uu = *(const unsigned int*)(QKV + (size_t)bs * 3072 + idx * 128 + d0);
  float x0 = bf2f((unsigned short)(uu & 0xffffu));
  float x1 = bf2f((unsigned short)(uu >> 16));
  if (idx < 20) {
    const float* nw = (idx < 16) ? qw : kw;
    float ss = x0 * x0 + x1 * x1;
#pragma unroll
    for (int mk = 1; mk < 64; mk <<= 1) ss += __shfl_xor(ss, mk);
    float inv = rsqrtf(ss * (1.0f / 128.0f) + 1e-6f);
    float n0 = x0 * inv * nw[d0], n1 = x1 * inv * nw[d0 + 1];
    float p0 = __shfl_xor(n0, 32), p1 = __shfl_xor(n1, 32);
    float sg = (l < 32) ? -1.0f : 1.0f;
    float c0 = cosT[s * 128 + d0], c1 = cosT[s * 128 + d0 + 1];
    float sn0 = sinT[s * 128 + d0], sn1 = sinT[s * 128 + d0 + 1];
    float o0 = n0 * c0 + sg * p0 * sn0;
    float o1 = n1 * c1 + sg * p1 * sn1;
    int mf = d0 >> 4, hi = (d0 >> 3) & 1, j = d0 & 7;
    int blk = s >> 5, r31 = s & 31;
    int foff = (mf * 2 + hi) * 256 + r31 * 8 + j;
    unsigned short* dst;
    if (idx < 16) {
      const float qs = 0.08838834764831845f * 1.4426950408889634f;  // 1/sqrt(128)*log2e
      o0 *= qs; o1 *= qs;
      dst = Qpk + (((size_t)(b * 16 + idx)) * 64 + blk) * 4096 + foff;
    } else {
      dst = Kpk + (((size_t)(b * 4 + (idx - 16))) * 64 + blk) * 4096 + foff;
    }
    *(unsigned int*)dst = pk2(o0, o1);
  } else {
    int kvh = idx - 20;
    // V in 32-kv blocks: blk = s>>5, ks = (s>>4)&1, his=(s>>3)&1, j=s&7
    int blk = s >> 5, ks = (s >> 4) & 1, his = (s >> 3) & 1, j = s & 7;
    int n = d0 >> 5, d31 = d0 & 31;
    size_t base = (((size_t)(b * 4 + kvh)) * 64 + blk) * 4096 +
                  (((n * 2 + ks) * 2 + his) * 256 + d31 * 8 + j);
    Vpk[base] = f2bf(x0);
    Vpk[base + 8] = f2bf(x1);   // d0+1 -> d31+1
  }
}

// ---------------- flash attention: 8-wave KV-split, triple-buf, 1 barrier/round ----
// 256 blocks x 8 waves (512 thr). bid&7 -> (b,kvh) (XCD-pinned K/V);
// pj=bid>>3: block runs strip 63-pj then strip pj (rounds/block = 33-34, equal).
// Waves: grp = w>>2 (KV-half group), hw = w&3 (head). Per strip: nt = strip+1
// KV tiles of 32; g0 owns tiles [0,hcut), g1 owns [hcut,nt); private online
// softmax state; in-LDS flash combine at strip end (epilogue = __syncthreads,
// cold path). Staging: 3 LDS buffers/group, one s_barrier per round: round r
// reads buf r%3, writes buf (r+2)%3 -- disjoint, and (r+2)%3 was last read in
// window r-1, separated by barrier r.
// LDS map: [0,96K) = 6 staging buffers (buf*2+grp)*16K; [96K..98K) ob overlap
// region is inside buffers (used only in epilogue after all reads);
// [98304,100352) = mlb m/l exchange (IN BOUNDS now).
__global__ __launch_bounds__(512) void attn_kernel(
    const unsigned short* __restrict__ Qpk, const unsigned short* __restrict__ Kpk,
    const unsigned short* __restrict__ Vpk, unsigned short* __restrict__ Y) {
  __shared__ __attribute__((aligned(16))) unsigned char lds_raw[100352];
  const int t = threadIdx.x, w = t >> 6, l = t & 63;
  const int q31 = l & 31, hi = l >> 5;
  const int grp = w >> 2, hw = w & 3;
  const int bid = blockIdx.x;
  const int xcd = bid & 7;
  const int b = xcd >> 2, kvh = xcd & 3;
  const int hd = kvh * 4 + hw;
  const int bh = b * 16 + hd;
  const int pj = bid >> 3;
  const unsigned short* Kg = Kpk + (size_t)(b * 4 + kvh) * 262144;
  const unsigned short* Vg = Vpk + (size_t)(b * 4 + kvh) * 262144;
  float* mlb = (float*)(lds_raw + 98304);   // [head][grp][{m,l}][q31], 2KB

#define STAGE1(st, buf)                                                        \
  {                                                                            \
    unsigned char* base_ = lds_raw + ((buf) * 2 + grp) * 16384;                \
    const unsigned short* kg_ = Kg + (size_t)(st) * 4096;                      \
    const unsigned short* vg_ = Vg + (size_t)(st) * 4096;                      \
    _Pragma("unroll")                                                          \
    for (int i_ = 0; i_ < 4; i_++) {                                           \
      int c_ = hw * 4 + i_;                                                    \
      const unsigned short* src_ = (c_ < 8) ? (kg_ + c_ * 512 + l * 8)         \
                                            : (vg_ + (c_ - 8) * 512 + l * 8);  \
      async16(src_, base_ + c_ * 1024 + l * 16);                               \
    }                                                                          \
  }

  for (int phase = 0; phase < 2; phase++) {
    const int strip = phase ? pj : (63 - pj);
    const int q0w = strip * 32;
    const int qg = q0w + q31;
    const int nt = strip + 1;
    const int hcut = (nt + 1) >> 1;
    const int myFirst = grp ? hcut : 0;
    const int myCnt = grp ? (nt - hcut) : hcut;
    const int R = hcut;

    const unsigned short* Qs = Qpk + (((size_t)bh * 64 + strip) * 4096) + (size_t)l * 8;
    bf16x8 qf[8];
#pragma unroll
    for (int mf = 0; mf < 8; mf++) qf[mf] = ldfrag(Qs + mf * 512);
    asm volatile("s_waitcnt vmcnt(0)" ::: "memory");  // Q resolved; vmcnt exact

    { int st0 = (myCnt > 0) ? myFirst : 0; STAGE1(st0, 0); }

    f32x16 o[4];
#pragma unroll
    for (int n = 0; n < 4; n++) o[n] = zero16();
    float m = -3.0e38f, lsum = 0.f;

    for (int r = 0; r < R; r++) {
      const int buf = r % 3;
      { int st = (r + 1 < myCnt) ? (myFirst + r + 1) : 0; STAGE1(st, (r + 1) % 3); }
      asm volatile("s_waitcnt vmcnt(4)" ::: "memory");  // my round-r stage landed; next in flight
      __builtin_amdgcn_s_barrier();
      __builtin_amdgcn_sched_barrier(0);

      if (r < myCnt) {
        const int ti = myFirst + r;
        const int kv0 = ti << 5;
        const unsigned short* base =
            (const unsigned short*)(lds_raw + (buf * 2 + grp) * 16384);
        // ---- QK^T (swapped): two 4-deep chains, then merge ----
        f32x16 sA = zero16(), sB = zero16();
        __builtin_amdgcn_s_setprio(1);
#pragma unroll
        for (int mf = 0; mf < 4; mf++) {
          sA = mfma32(ldfrag(base + mf * 512 + l * 8), qf[mf], sA);
          sB = mfma32(ldfrag(base + (mf + 4) * 512 + l * 8), qf[mf + 4], sB);
        }
        __builtin_amdgcn_s_setprio(0);
#pragma unroll
        for (int rr = 0; rr < 16; rr++) sA[rr] += sB[rr];
        // ---- causal mask (diagonal tile only) ----
        if (ti == nt - 1) {
#pragma unroll
          for (int rr = 0; rr < 16; rr++) {
            int kv = kv0 + (rr & 3) + 8 * (rr >> 2) + 4 * hi;
            if (kv > qg) sA[rr] = -3.0e38f;
          }
        }
        // ---- online softmax (lane-local row, exp2 units) ----
        float pm = sA[0];
#pragma unroll
        for (int rr = 1; rr < 16; rr++) pm = fmaxf(pm, sA[rr]);
        pm = fmaxf(pm, __shfl_xor(pm, 32));
        if (__any(pm > m + 8.0f)) {   // defer-max
          float mn = fmaxf(m, pm);
          float scl = exp2f(m - mn);
          m = mn; lsum *= scl;
#pragma unroll
          for (int rr = 0; rr < 16; rr++) {
            float sr = __shfl(scl, (rr & 3) + 8 * (rr >> 2) + 4 * hi);
            o[0][rr] *= sr; o[1][rr] *= sr; o[2][rr] *= sr; o[3][rr] *= sr;
          }
        }
#pragma unroll
        for (int rr = 0; rr < 16; rr++) sA[rr] = exp2f(sA[rr] - m);
        float ts = 0.f;
#pragma unroll
        for (int rr = 0; rr < 16; rr++) ts += sA[rr];
        ts += __shfl_xor(ts, 32);
        lsum += ts;
        // ---- pack P -> A-operand fragments (register exchange) ----
        bf16x8 paf[2];
#pragma unroll
        for (int f = 0; f < 2; f++) {
          const int bs8 = 8 * f;
          unsigned g00 = cvtpk(sA[bs8 + 0], sA[bs8 + 1]);
          unsigned g01 = cvtpk(sA[bs8 + 2], sA[bs8 + 3]);
          unsigned g10 = cvtpk(sA[bs8 + 4], sA[bs8 + 5]);
          unsigned g11 = cvtpk(sA[bs8 + 6], sA[bs8 + 7]);
          unsigned snd0 = hi ? g00 : g10;
          unsigned snd1 = hi ? g01 : g11;
          unsigned r0 = (unsigned)__shfl_xor((int)snd0, 32);
          unsigned r1 = (unsigned)__shfl_xor((int)snd1, 32);
          unsigned own0 = hi ? g10 : g00;
          unsigned own1 = hi ? g11 : g01;
          u32x4 wv;
          wv.x = hi ? r0 : own0;
          wv.y = hi ? r1 : own1;
          wv.z = hi ? own0 : r0;
          wv.w = hi ? own1 : r1;
          paf[f] = __builtin_bit_cast(bf16x8, wv);
        }
        // ---- PV ----
        __builtin_amdgcn_s_setprio(1);
#pragma unroll
        for (int n = 0; n < 4; n++) {
          o[n] = mfma32(paf[0], ldfrag(base + 4096 + (n * 2 + 0) * 512 + l * 8), o[n]);
          o[n] = mfma32(paf[1], ldfrag(base + 4096 + (n * 2 + 1) * 512 + l * 8), o[n]);
        }
        __builtin_amdgcn_s_setprio(0);
      }
      // no second barrier: triple buffer makes restage of (r+2)%3 safe
    }

    // ---- combine the two KV-half partials (in LDS; cold path, full syncs) ----
    __syncthreads();
    if (l < 32) {
      mlb[hw * 128 + grp * 64 + q31] = m;
      mlb[hw * 128 + grp * 64 + 32 + q31] = lsum;
    }
    __syncthreads();
    float m_o = mlb[hw * 128 + (grp ^ 1) * 64 + q31];
    float l_o = mlb[hw * 128 + (grp ^ 1) * 64 + 32 + q31];
    float M = fmaxf(m, m_o);
    float sc = exp2f(m - M);
    float lF = lsum * sc + l_o * exp2f(m_o - M);
    // scale own O by sc (per q-row)
#pragma unroll
    for (int rr = 0; rr < 16; rr++) {
      float sr = __shfl(sc, (rr & 3) + 8 * (rr >> 2) + 4 * hi);
      o[0][rr] *= sr; o[1][rr] *= sr; o[2][rr] *= sr; o[3][rr] *= sr;
    }
    float* ob = (float*)lds_raw + hw * 4096;   // [q32][d128] per head (overlaps bufs, dead now)
    if (grp == 1) {
#pragma unroll
      for (int rr = 0; rr < 16; rr++) {
        int cr = (rr & 3) + 8 * (rr >> 2) + 4 * hi;
#pragma unroll
        for (int n = 0; n < 4; n++) ob[cr * 128 + n * 32 + q31] = o[n][rr];
      }
    }
    __syncthreads();
    if (grp == 0) {
      float linv = 1.0f / lF;
#pragma unroll
      for (int rr = 0; rr < 16; rr++) {
        int cr = (rr & 3) + 8 * (rr >> 2) + 4 * hi;
        float lr = __shfl(linv, cr);
        int qrow = q0w + cr;
        size_t rowoff = ((size_t)(b * S_LEN + qrow)) * 2048 + hd * 128 + q31;
        Y[rowoff]      = f2bf((o[0][rr] + ob[cr * 128 + q31]) * lr);
        Y[rowoff + 32] = f2bf((o[1][rr] + ob[cr * 128 + 32 + q31]) * lr);
        Y[rowoff + 64] = f2bf((o[2][rr] + ob[cr * 128 + 64 + q31]) * lr);
        Y[rowoff + 96] = f2bf((o[3][rr] + ob[cr * 128 + 96 + q31]) * lr);
      }
    }
    __syncthreads();   // Obuf consumed before next phase restages
  }
#undef STAGE1
}

// ---------------- launch ----------------
extern "C" void kernel_launch(void* const* d_in, const int* in_sizes, int n_in,
                              void* d_out, int out_size, void* d_ws, size_t ws_size,
                              hipStream_t stream) {
  const float* x  = (const float*)d_in[0];
  const float* rc = (const float*)d_in[1];
  const float* rs = (const float*)d_in[2];
  const float* Wq = (const float*)d_in[3];
  const float* Wk = (const float*)d_in[4];
  const float* Wv = (const float*)d_in[5];
  const float* Wo = (const float*)d_in[6];
  const float* qw = (const float*)d_in[7];
  const float* kw = (const float*)d_in[8];
  float* out = (float*)d_out;
  char* ws = (char*)d_ws;

  unsigned short* xb   = (unsigned short*)(ws + 0);
  unsigned short* WT   = (unsigned short*)(ws + 16777216);
  unsigned short* WoT  = (unsigned short*)(ws + 29360128);
  unsigned short* QKVb = (unsigned short*)(ws + 37748736);
  unsigned short* Qpk  = (unsigned short*)(ws + 0);          // over xb (dead)
  unsigned short* Kpk  = (unsigned short*)(ws + 16777216);   // over WT (dead)
  unsigned short* Vpk  = (unsigned short*)(ws + 20971520);   // over WT (dead)
  unsigned short* Yb   = (unsigned short*)(ws + 37748736);   // over QKVb (dead)

  cast_x_kernel<<<4096, 256, 0, stream>>>(x, xb, 1048576);
  transpose_cast_kernel<<<dim3(32, 32), 256, 0, stream>>>(Wq, WT, 2048, 2048, 0, 2048);
  transpose_cast_kernel<<<dim3(8, 32), 256, 0, stream>>>(Wk, WT, 2048, 512, 2048, 2048);
  transpose_cast_kernel<<<dim3(8, 32), 256, 0, stream>>>(Wv, WT, 2048, 512, 2560, 2048);
  transpose_cast_kernel<<<dim3(32, 32), 256, 0, stream>>>(Wo, WoT, 2048, 2048, 0, 2048);
  gemm_bf16_kernel<<<dim3(24, 32), 256, 0, stream>>>(xb, WT, QKVb, 4096, 3072, 2048, 1);
  mid_kernel<<<24576, 256, 0, stream>>>(QKVb, rc, rs, qw, kw, Qpk, Kpk, Vpk);
  attn_kernel<<<256, 512, 0, stream>>>(Qpk, Kpk, Vpk, Yb);
  gemm_bf16_kernel<<<dim3(16, 32), 256, 0, stream>>>(Yb, WoT, out, 4096, 2048, 2048, 0);
}